// Round 1
// baseline (900.885 us; speedup 1.0000x reference)
//
#include <hip/hip_runtime.h>

#define DEVFN __device__ __forceinline__

constexpr int B  = 16;
constexpr int C  = 256;
constexpr int HH = 64;
constexpr int WWID = 64;
constexpr int N  = HH * WWID;   // 4096
constexpr int O1 = C + 4;       // 260

DEVFN float gelu_exact(float x){
  return 0.5f * x * (1.0f + erff(x * 0.7071067811865476f));
}

// ---------------- K1: conv1x1  t[o,p] = sum_c W[o,c] x[c,p] + b[o] ----------
// grid (1024 pixel-tiles, 5 output-tiles), 256 threads.
// Block tile: 64 outputs x 64 pixels; thread: 4 outputs x 4 pixels.
__global__ __launch_bounds__(256)
void k_conv1(const float* __restrict__ x, const float* __restrict__ w,
             const float* __restrict__ bias, float* __restrict__ ctx,
             float* __restrict__ gates){
  __shared__ __align__(16) float wt[256 * 64];   // [c][row]
  __shared__ float bs[64];
  const int tid = threadIdx.x;
  const int tx = tid & 15, ty = tid >> 4;
  const int oBase = blockIdx.y * 64;
  for(int idx = tid; idx < 256 * 64; idx += 256){
    int c = idx >> 6, row = idx & 63;
    int o = oBase + row;
    wt[idx] = (o < O1) ? w[o * 256 + c] : 0.0f;
  }
  if(tid < 64){
    int o = oBase + tid;
    bs[tid] = (o < O1) ? bias[o] : 0.0f;
  }
  __syncthreads();
  const int pg = blockIdx.x * 64 + tx * 4;   // global pixel
  const int b  = pg >> 12;
  const int n  = pg & 4095;
  const float* xp = x + (size_t)b * C * N + n;
  float acc[4][4];
  #pragma unroll
  for(int i = 0; i < 4; i++)
    #pragma unroll
    for(int j = 0; j < 4; j++) acc[i][j] = 0.f;
  #pragma unroll 4
  for(int c = 0; c < 256; c++){
    const float4 xv = *(const float4*)(xp + (size_t)c * N);
    const float4 wv = *(const float4*)&wt[c * 64 + ty * 4];
    const float wa[4] = {wv.x, wv.y, wv.z, wv.w};
    const float xa[4] = {xv.x, xv.y, xv.z, xv.w};
    #pragma unroll
    for(int i = 0; i < 4; i++)
      #pragma unroll
      for(int j = 0; j < 4; j++)
        acc[i][j] = fmaf(wa[i], xa[j], acc[i][j]);
  }
  #pragma unroll
  for(int i = 0; i < 4; i++){
    int o = oBase + ty * 4 + i;
    if(o >= O1) continue;
    float bb = bs[ty * 4 + i];
    float4 r;
    r.x = acc[i][0] + bb; r.y = acc[i][1] + bb;
    r.z = acc[i][2] + bb; r.w = acc[i][3] + bb;
    if(o < 256){
      *(float4*)(ctx + ((size_t)(b * 256 + o)) * N + n) = r;
    } else {
      *(float4*)(gates + ((size_t)(b * 4 + (o - 256))) * N + n) = r;
    }
  }
}

// ---------------- depthwise conv + gelu + gated ctx_all accumulate ----------
// One block per (b,c) plane. Thread computes one 16-wide row segment.
template<int K, int GATE, bool FIRST, bool WRITE_OUT, bool REDUCE>
__global__ __launch_bounds__(256)
void k_dw(const float* __restrict__ in, const float* __restrict__ fw,
          const float* __restrict__ gates, float* __restrict__ outbuf,
          float* __restrict__ ctx_all, float* __restrict__ gsum){
  constexpr int R = K / 2;
  constexpr int ROWS = 64 + 2 * R;
  constexpr int STRIDE = 76;                  // 304B rows: 16B aligned, odd*16
  __shared__ __align__(16) float sm[ROWS * STRIDE];
  __shared__ float wk[K * K];
  __shared__ float red[256];
  const int tid = threadIdx.x;
  const int plane = blockIdx.x;               // b*256 + c
  const int b = plane >> 8;
  const int c = plane & 255;
  const float* ip = in + (size_t)plane * N;
  if(tid < K * K) wk[tid] = fw[c * K * K + tid];
  for(int idx = tid; idx < ROWS * STRIDE; idx += 256){
    int iy = idx / STRIDE, ix = idx - iy * STRIDE;
    int gy = iy - R, gx = ix - 4;
    float v = 0.f;
    if(gy >= 0 && gy < 64 && gx >= 0 && gx < 64) v = ip[gy * 64 + gx];
    sm[idx] = v;
  }
  __syncthreads();
  const int h  = tid >> 2;
  const int w0 = (tid & 3) * 16;
  float acc[16];
  #pragma unroll
  for(int p = 0; p < 16; p++) acc[p] = 0.f;
  #pragma unroll
  for(int ky = 0; ky < K; ky++){
    float rowreg[24];
    const float* rp = &sm[(h + ky) * STRIDE + w0];   // covers gx in [w0-4, w0+20)
    #pragma unroll
    for(int q = 0; q < 6; q++){
      float4 v4 = *(const float4*)(rp + q * 4);
      rowreg[q*4+0] = v4.x; rowreg[q*4+1] = v4.y;
      rowreg[q*4+2] = v4.z; rowreg[q*4+3] = v4.w;
    }
    #pragma unroll
    for(int kx = 0; kx < K; kx++){
      float wv = wk[ky * K + kx];
      #pragma unroll
      for(int p = 0; p < 16; p++)
        acc[p] = fmaf(rowreg[p + kx + 4 - R], wv, acc[p]);
    }
  }
  const int nbase = h * 64 + w0;
  const float* gp = gates + ((size_t)(b * 4 + GATE)) * N + nbase;
  float* cap = ctx_all + (size_t)plane * N + nbase;
  float gs_local = 0.f;
  #pragma unroll
  for(int q = 0; q < 4; q++){
    float g[4];
    #pragma unroll
    for(int j = 0; j < 4; j++){
      g[j] = gelu_exact(acc[q * 4 + j]);
      if(REDUCE) gs_local += g[j];
    }
    float4 gt = *(const float4*)(gp + q * 4);
    float4 res;
    if(FIRST){
      res.x = g[0] * gt.x; res.y = g[1] * gt.y;
      res.z = g[2] * gt.z; res.w = g[3] * gt.w;
    } else {
      float4 prev = *(const float4*)(cap + q * 4);
      res.x = prev.x + g[0] * gt.x; res.y = prev.y + g[1] * gt.y;
      res.z = prev.z + g[2] * gt.z; res.w = prev.w + g[3] * gt.w;
    }
    *(float4*)(cap + q * 4) = res;
    if(WRITE_OUT){
      float4 og; og.x = g[0]; og.y = g[1]; og.z = g[2]; og.w = g[3];
      *(float4*)(outbuf + (size_t)plane * N + nbase + q * 4) = og;
    }
  }
  if(REDUCE){
    red[tid] = gs_local;
    __syncthreads();
    for(int s = 128; s > 0; s >>= 1){
      if(tid < s) red[tid] += red[tid + s];
      __syncthreads();
    }
    if(tid == 0) gsum[plane] = red[0] * (1.0f / 4096.0f);
  }
}

// ---------------- s_key[b] = sum_c key_w[c] * G[b,c] ----------
__global__ __launch_bounds__(256)
void k_skey(const float* __restrict__ G, const float* __restrict__ key_w,
            float* __restrict__ s_key){
  __shared__ float red[256];
  int b = blockIdx.x, tid = threadIdx.x;
  red[tid] = key_w[tid] * G[b * 256 + tid];
  __syncthreads();
  for(int s = 128; s > 0; s >>= 1){
    if(tid < s) red[tid] += red[tid + s];
    __syncthreads();
  }
  if(tid == 0) s_key[b] = red[0];
}

// ---------------- logits[b,n] = sum_c kw[c]*P[b,c,n] + kb + s_key[b]*g3 ------
__global__ __launch_bounds__(256)
void k_logits(const float* __restrict__ P, const float* __restrict__ key_w,
              const float* __restrict__ key_b, const float* __restrict__ s_key,
              const float* __restrict__ gates, float* __restrict__ logits){
  __shared__ float kw[256];
  __shared__ float part[256];
  int tid = threadIdx.x;
  kw[tid] = key_w[tid];
  __syncthreads();
  int b = blockIdx.x >> 6;
  int n0 = (blockIdx.x & 63) * 64;
  int cpart = tid >> 6, px = tid & 63;
  const float* pp = P + ((size_t)(b * 256 + cpart * 64)) * N + n0 + px;
  float acc = 0.f;
  #pragma unroll 8
  for(int c = 0; c < 64; c++)
    acc = fmaf(kw[cpart * 64 + c], pp[(size_t)c * N], acc);
  part[tid] = acc;
  __syncthreads();
  if(tid < 64){
    float l = part[tid] + part[64 + tid] + part[128 + tid] + part[192 + tid];
    float g3 = gates[((size_t)(b * 4 + 3)) * N + n0 + tid];
    logits[b * N + n0 + tid] = l + key_b[0] + s_key[b] * g3;
  }
}

// ---------------- softmax over N per batch, and kg3[b] = sum k*g3 ----------
__global__ __launch_bounds__(256)
void k_softmax(float* __restrict__ kbuf, const float* __restrict__ gates,
               float* __restrict__ kg3){
  __shared__ float red[256];
  int b = blockIdx.x, tid = threadIdx.x;
  float v[16];
  float m = -1e30f;
  #pragma unroll
  for(int i = 0; i < 16; i++){
    v[i] = kbuf[b * N + tid + i * 256];
    m = fmaxf(m, v[i]);
  }
  red[tid] = m; __syncthreads();
  for(int s = 128; s > 0; s >>= 1){
    if(tid < s) red[tid] = fmaxf(red[tid], red[tid + s]);
    __syncthreads();
  }
  m = red[0]; __syncthreads();
  float ssum = 0.f;
  #pragma unroll
  for(int i = 0; i < 16; i++){ v[i] = expf(v[i] - m); ssum += v[i]; }
  red[tid] = ssum; __syncthreads();
  for(int s = 128; s > 0; s >>= 1){
    if(tid < s) red[tid] += red[tid + s];
    __syncthreads();
  }
  float inv = 1.0f / red[0];
  __syncthreads();
  float kg = 0.f;
  #pragma unroll
  for(int i = 0; i < 16; i++){
    float k = v[i] * inv;
    kbuf[b * N + tid + i * 256] = k;
    kg += k * gates[((size_t)(b * 4 + 3)) * N + tid + i * 256];
  }
  red[tid] = kg; __syncthreads();
  for(int s = 128; s > 0; s >>= 1){
    if(tid < s) red[tid] += red[tid + s];
    __syncthreads();
  }
  if(tid == 0) kg3[b] = red[0];
}

// ---------------- qk[b,c] = sum_n P[b,c,n]*k[b,n] + G[b,c]*kg3[b] ----------
__global__ __launch_bounds__(256)
void k_qk(const float* __restrict__ P, const float* __restrict__ kbuf,
          const float* __restrict__ G, const float* __restrict__ kg3,
          float* __restrict__ qk){
  __shared__ float red[256];
  int plane = blockIdx.x, tid = threadIdx.x;
  int b = plane >> 8;
  const float* pp = P + (size_t)plane * N;
  const float* kp = kbuf + b * N;
  float acc = 0.f;
  #pragma unroll
  for(int i = 0; i < 16; i++){
    int n = tid + i * 256;
    acc = fmaf(pp[n], kp[n], acc);
  }
  red[tid] = acc; __syncthreads();
  for(int s = 128; s > 0; s >>= 1){
    if(tid < s) red[tid] += red[tid + s];
    __syncthreads();
  }
  if(tid == 0) qk[plane] = red[0] + G[plane] * kg3[b];
}

// ---------------- v pipeline per batch: v1 -> LN -> relu -> v2 ----------
__global__ __launch_bounds__(256)
void k_v(const float* __restrict__ qk, const float* __restrict__ v1w,
         const float* __restrict__ v1b, const float* __restrict__ lnw,
         const float* __restrict__ lnb, const float* __restrict__ v2w,
         const float* __restrict__ v2b, float* __restrict__ vout){
  int b = blockIdx.x, tid = threadIdx.x;
  __shared__ float qs[256];
  __shared__ float part[256];
  __shared__ float v1s[16];
  __shared__ float vr[16];
  __shared__ float stats[2];
  qs[tid] = qk[b * 256 + tid];
  __syncthreads();
  int oc = tid >> 4, ln = tid & 15;
  float p = 0.f;
  #pragma unroll
  for(int j = 0; j < 16; j++){
    int c = ln + j * 16;
    p = fmaf(v1w[oc * 256 + c], qs[c], p);
  }
  part[tid] = p;
  __syncthreads();
  if(tid < 16){
    float s = v1b[tid];
    for(int j = 0; j < 16; j++) s += part[tid * 16 + j];
    v1s[tid] = s;
  }
  __syncthreads();
  if(tid == 0){
    float mu = 0.f;
    for(int i = 0; i < 16; i++) mu += v1s[i];
    mu *= (1.f / 16.f);
    float var = 0.f;
    for(int i = 0; i < 16; i++){ float d = v1s[i] - mu; var += d * d; }
    var *= (1.f / 16.f);
    stats[0] = mu; stats[1] = rsqrtf(var + 1e-5f);
  }
  __syncthreads();
  if(tid < 16){
    float vv = (v1s[tid] - stats[0]) * stats[1] * lnw[tid] + lnb[tid];
    vr[tid] = fmaxf(vv, 0.f);
  }
  __syncthreads();
  float o = v2b[tid];
  #pragma unroll
  for(int j = 0; j < 16; j++) o = fmaf(v2w[tid * 16 + j], vr[j], o);
  vout[b * 256 + tid] = o;
}

// ---------------- out = P + G*g3 + vout (in place on d_out) ----------
__global__ __launch_bounds__(256)
void k_final(float* __restrict__ out, const float* __restrict__ G,
             const float* __restrict__ gates, const float* __restrict__ vout){
  int idx = blockIdx.x * 256 + threadIdx.x;   // float4 index
  int n4 = idx & 1023;
  int plane = idx >> 10;
  int b = plane >> 8;
  float4 p = *((float4*)out + idx);
  float4 g3 = *((const float4*)gates + (size_t)(b * 4 + 3) * 1024 + n4);
  float gg = G[plane], vv = vout[plane];
  p.x += gg * g3.x + vv; p.y += gg * g3.y + vv;
  p.z += gg * g3.z + vv; p.w += gg * g3.w + vv;
  *((float4*)out + idx) = p;
}

extern "C" void kernel_launch(void* const* d_in, const int* in_sizes, int n_in,
                              void* d_out, int out_size, void* d_ws, size_t ws_size,
                              hipStream_t stream){
  const float* x      = (const float*)d_in[0];
  const float* conv_w = (const float*)d_in[1];
  const float* conv_b = (const float*)d_in[2];
  const float* fw3    = (const float*)d_in[3];
  const float* fw5    = (const float*)d_in[4];
  const float* fw7    = (const float*)d_in[5];
  const float* key_w  = (const float*)d_in[6];
  const float* key_b  = (const float*)d_in[7];
  const float* v1_w   = (const float*)d_in[8];
  const float* v1_b   = (const float*)d_in[9];
  const float* ln_w   = (const float*)d_in[10];
  const float* ln_b   = (const float*)d_in[11];
  const float* v2_w   = (const float*)d_in[12];
  const float* v2_b   = (const float*)d_in[13];
  float* out = (float*)d_out;
  float* ws  = (float*)d_ws;

  const size_t PL = (size_t)B * C * N;     // 16,777,216 floats
  float* ctxA  = ws;
  float* ctxB  = ws + PL;
  float* gates = ws + 2 * PL;              // B*4*N
  float* G     = gates + (size_t)B * 4 * N;
  float* s_key = G + B * C;
  float* kbuf  = s_key + 16;               // B*N
  float* kg3   = kbuf + (size_t)B * N;
  float* qkb   = kg3 + 16;                 // B*C
  float* vout  = qkb + B * C;              // B*C

  // 1. conv1x1 -> ctxA (256 ch) + gates (4 ch)
  k_conv1<<<dim3(1024, 5), 256, 0, stream>>>(x, conv_w, conv_b, ctxA, gates);
  // 2. dw3 + gelu: ctxA -> ctxB; d_out(ctx_all) = ctxB * g0
  k_dw<3, 0, true,  true,  false><<<B * C, 256, 0, stream>>>(ctxA, fw3, gates, ctxB, out, G);
  // 3. dw5 + gelu: ctxB -> ctxA; d_out += ctxA * g1
  k_dw<5, 1, false, true,  false><<<B * C, 256, 0, stream>>>(ctxB, fw5, gates, ctxA, out, G);
  // 4. dw7 + gelu: ctxA -> (mean only); d_out += ctx * g2; G = plane means
  k_dw<7, 2, false, false, true ><<<B * C, 256, 0, stream>>>(ctxA, fw7, gates, ctxB, out, G);
  // 5. s_key[b] = key_w . G[b,:]
  k_skey<<<B, 256, 0, stream>>>(G, key_w, s_key);
  // 6. logits
  k_logits<<<1024, 256, 0, stream>>>(out, key_w, key_b, s_key, gates, kbuf);
  // 7. softmax + kg3
  k_softmax<<<B, 256, 0, stream>>>(kbuf, gates, kg3);
  // 8. qk
  k_qk<<<B * C, 256, 0, stream>>>(out, kbuf, G, kg3, qkb);
  // 9. v pipeline
  k_v<<<B, 256, 0, stream>>>(qkb, v1_w, v1_b, ln_w, ln_b, v2_w, v2_b, vout);
  // 10. final: out = P + G*g3 + vout
  k_final<<<16384, 256, 0, stream>>>(out, G, gates, vout);
}

// Round 2
// 575.651 us; speedup vs baseline: 1.5650x; 1.5650x over previous
//
#include <hip/hip_runtime.h>

#define DEVFN __device__ __forceinline__

constexpr int B  = 16;
constexpr int C  = 256;
constexpr int N  = 64 * 64;     // 4096
constexpr int O1 = C + 4;       // 260

DEVFN float gelu_exact(float x){
  return 0.5f * x * (1.0f + erff(x * 0.7071067811865476f));
}

// ---------------- K1: conv1x1  t[o,p] = sum_c W[o,c] x[c,p] + b[o] ----------
// Block: 64 outputs x 256 pixels, 256 threads (thread = 4 out x 16 px).
// W staged per 64-c chunk (17KB LDS). Grid (256 px-tiles, 5 o-tiles).
__global__ __launch_bounds__(256, 4)
void k_conv1(const float* __restrict__ x, const float* __restrict__ w,
             const float* __restrict__ bias, float* __restrict__ ctx,
             float* __restrict__ gates){
  __shared__ __align__(16) float wt[64 * 68];   // [c_local][o_row], stride 68
  const int tid = threadIdx.x;
  const int tx = tid & 15;          // pixel group
  const int ty = tid >> 4;          // output group (4 outputs)
  const int oBase = blockIdx.y * 64;
  const int pg0 = blockIdx.x * 256; // block pixel base (within one batch)
  const int b  = pg0 >> 12;
  const int n0 = pg0 & 4095;
  const float* xbase = x + (size_t)b * C * N + n0 + tx * 4;

  float acc[4][16];
  #pragma unroll
  for(int i = 0; i < 4; i++)
    #pragma unroll
    for(int p = 0; p < 16; p++) acc[i][p] = 0.f;

  for(int c0 = 0; c0 < 256; c0 += 64){
    __syncthreads();
    #pragma unroll
    for(int i = 0; i < 16; i++){
      int idx = tid + i * 256;          // 0..4095
      int o_row = idx >> 6, c_l = idx & 63;
      int o = oBase + o_row;
      wt[c_l * 68 + o_row] = (o < O1) ? w[o * 256 + c0 + c_l] : 0.f;
    }
    __syncthreads();
    const float* xc = xbase + (size_t)c0 * N;
    #pragma unroll 2
    for(int cl = 0; cl < 64; cl++){
      const float* xr = xc + (size_t)cl * N;
      float4 xv0 = *(const float4*)(xr);
      float4 xv1 = *(const float4*)(xr + 64);
      float4 xv2 = *(const float4*)(xr + 128);
      float4 xv3 = *(const float4*)(xr + 192);
      float4 wv = *(const float4*)&wt[cl * 68 + ty * 4];
      const float wa[4] = {wv.x, wv.y, wv.z, wv.w};
      #pragma unroll
      for(int i = 0; i < 4; i++){
        acc[i][ 0] = fmaf(wa[i], xv0.x, acc[i][ 0]);
        acc[i][ 1] = fmaf(wa[i], xv0.y, acc[i][ 1]);
        acc[i][ 2] = fmaf(wa[i], xv0.z, acc[i][ 2]);
        acc[i][ 3] = fmaf(wa[i], xv0.w, acc[i][ 3]);
        acc[i][ 4] = fmaf(wa[i], xv1.x, acc[i][ 4]);
        acc[i][ 5] = fmaf(wa[i], xv1.y, acc[i][ 5]);
        acc[i][ 6] = fmaf(wa[i], xv1.z, acc[i][ 6]);
        acc[i][ 7] = fmaf(wa[i], xv1.w, acc[i][ 7]);
        acc[i][ 8] = fmaf(wa[i], xv2.x, acc[i][ 8]);
        acc[i][ 9] = fmaf(wa[i], xv2.y, acc[i][ 9]);
        acc[i][10] = fmaf(wa[i], xv2.z, acc[i][10]);
        acc[i][11] = fmaf(wa[i], xv2.w, acc[i][11]);
        acc[i][12] = fmaf(wa[i], xv3.x, acc[i][12]);
        acc[i][13] = fmaf(wa[i], xv3.y, acc[i][13]);
        acc[i][14] = fmaf(wa[i], xv3.z, acc[i][14]);
        acc[i][15] = fmaf(wa[i], xv3.w, acc[i][15]);
      }
    }
  }

  #pragma unroll
  for(int i = 0; i < 4; i++){
    int o = oBase + ty * 4 + i;
    if(o >= O1) continue;
    float bb = bias[o];
    #pragma unroll
    for(int j = 0; j < 4; j++){
      float4 r;
      r.x = acc[i][j*4+0] + bb; r.y = acc[i][j*4+1] + bb;
      r.z = acc[i][j*4+2] + bb; r.w = acc[i][j*4+3] + bb;
      int px = n0 + j * 64 + tx * 4;
      if(o < 256)
        *(float4*)(ctx + ((size_t)(b * 256 + o)) * N + px) = r;
      else
        *(float4*)(gates + ((size_t)(b * 4 + (o - 256))) * N + px) = r;
    }
  }
}

// ---------------- fused depthwise chain ----------
// One block per (b,c) plane: dw3->gelu->dw5->gelu->dw7->gelu entirely in LDS,
// gated accumulation + global-mean term folded in; writes FULL ctx_all to out.
constexpr int DSTR = 76;   // LDS row stride (floats): 304B, 16B-aligned, odd*16
constexpr int DROWS = 70;  // rows -3..66 (halo 3)

template<int K>
DEVFN void dw_conv(const float* __restrict__ src, const float* __restrict__ wk,
                   int h, int w0, float* val){
  constexpr int R = K / 2;
  float acc[16];
  #pragma unroll
  for(int p = 0; p < 16; p++) acc[p] = 0.f;
  #pragma unroll
  for(int ky = 0; ky < K; ky++){
    const float* rp = &src[(h + 3 - R + ky) * DSTR + w0];  // gx in [w0-4, w0+20)
    float rowreg[24];
    #pragma unroll
    for(int q = 0; q < 6; q++){
      float4 v4 = *(const float4*)(rp + q * 4);
      rowreg[q*4+0] = v4.x; rowreg[q*4+1] = v4.y;
      rowreg[q*4+2] = v4.z; rowreg[q*4+3] = v4.w;
    }
    #pragma unroll
    for(int kx = 0; kx < K; kx++){
      float wv = wk[ky * K + kx];
      #pragma unroll
      for(int p = 0; p < 16; p++)
        acc[p] = fmaf(rowreg[p + kx + 4 - R], wv, acc[p]);
    }
  }
  #pragma unroll
  for(int p = 0; p < 16; p++) val[p] = gelu_exact(acc[p]);
}

__global__ __launch_bounds__(256)
void k_dwchain(const float* __restrict__ in, const float* __restrict__ fw3,
               const float* __restrict__ fw5, const float* __restrict__ fw7,
               const float* __restrict__ gates, float* __restrict__ out){
  __shared__ __align__(16) float bufA[DROWS * DSTR];
  __shared__ __align__(16) float bufB[DROWS * DSTR];
  __shared__ float wk3[9], wk5[25], wk7[49];
  __shared__ float red[256];
  const int tid = threadIdx.x;
  const int plane = blockIdx.x;
  const int b = plane >> 8;
  const int c = plane & 255;
  const float* ip = in + (size_t)plane * N;

  // zero both buffers + load weights
  for(int idx = tid; idx < DROWS * DSTR; idx += 256){ bufA[idx] = 0.f; bufB[idx] = 0.f; }
  if(tid < 9)  wk3[tid] = fw3[c * 9 + tid];
  if(tid < 25) wk5[tid] = fw5[c * 25 + tid];
  if(tid < 49) wk7[tid] = fw7[c * 49 + tid];
  __syncthreads();
  // load interior of A (float4, coalesced)
  const float4* ip4 = (const float4*)ip;
  #pragma unroll
  for(int i = 0; i < 4; i++){
    int idx4 = tid + i * 256;            // 0..1023
    int gy = idx4 >> 4, gx4 = (idx4 & 15) * 4;
    *(float4*)&bufA[(gy + 3) * DSTR + gx4 + 4] = ip4[idx4];
  }
  __syncthreads();

  const int h  = tid >> 2;
  const int w0 = (tid & 3) * 16;
  const int nbase = h * 64 + w0;
  const float* g0p = gates + ((size_t)(b * 4 + 0)) * N + nbase;
  const float* g1p = gates + ((size_t)(b * 4 + 1)) * N + nbase;
  const float* g2p = gates + ((size_t)(b * 4 + 2)) * N + nbase;
  const float* g3p = gates + ((size_t)(b * 4 + 3)) * N + nbase;

  float ctxp[16];
  #pragma unroll
  for(int p = 0; p < 16; p++) ctxp[p] = 0.f;
  float val[16];

  // stage 1: dw3 on A -> B
  dw_conv<3>(bufA, wk3, h, w0, val);
  #pragma unroll
  for(int q = 0; q < 4; q++){
    float4 g = *(const float4*)(g0p + q * 4);
    ctxp[q*4+0] = fmaf(val[q*4+0], g.x, ctxp[q*4+0]);
    ctxp[q*4+1] = fmaf(val[q*4+1], g.y, ctxp[q*4+1]);
    ctxp[q*4+2] = fmaf(val[q*4+2], g.z, ctxp[q*4+2]);
    ctxp[q*4+3] = fmaf(val[q*4+3], g.w, ctxp[q*4+3]);
    float4 vv; vv.x = val[q*4+0]; vv.y = val[q*4+1]; vv.z = val[q*4+2]; vv.w = val[q*4+3];
    *(float4*)&bufB[(h + 3) * DSTR + w0 + 4 + q * 4] = vv;
  }
  __syncthreads();

  // stage 2: dw5 on B -> A
  dw_conv<5>(bufB, wk5, h, w0, val);
  #pragma unroll
  for(int q = 0; q < 4; q++){
    float4 g = *(const float4*)(g1p + q * 4);
    ctxp[q*4+0] = fmaf(val[q*4+0], g.x, ctxp[q*4+0]);
    ctxp[q*4+1] = fmaf(val[q*4+1], g.y, ctxp[q*4+1]);
    ctxp[q*4+2] = fmaf(val[q*4+2], g.z, ctxp[q*4+2]);
    ctxp[q*4+3] = fmaf(val[q*4+3], g.w, ctxp[q*4+3]);
    float4 vv; vv.x = val[q*4+0]; vv.y = val[q*4+1]; vv.z = val[q*4+2]; vv.w = val[q*4+3];
    *(float4*)&bufA[(h + 3) * DSTR + w0 + 4 + q * 4] = vv;
  }
  __syncthreads();

  // stage 3: dw7 on A -> regs; accumulate + local sum for plane mean
  dw_conv<7>(bufA, wk7, h, w0, val);
  float lsum = 0.f;
  #pragma unroll
  for(int q = 0; q < 4; q++){
    float4 g = *(const float4*)(g2p + q * 4);
    ctxp[q*4+0] = fmaf(val[q*4+0], g.x, ctxp[q*4+0]);
    ctxp[q*4+1] = fmaf(val[q*4+1], g.y, ctxp[q*4+1]);
    ctxp[q*4+2] = fmaf(val[q*4+2], g.z, ctxp[q*4+2]);
    ctxp[q*4+3] = fmaf(val[q*4+3], g.w, ctxp[q*4+3]);
    lsum += val[q*4+0] + val[q*4+1] + val[q*4+2] + val[q*4+3];
  }
  red[tid] = lsum;
  __syncthreads();
  for(int s = 128; s > 0; s >>= 1){
    if(tid < s) red[tid] += red[tid + s];
    __syncthreads();
  }
  const float mean = red[0] * (1.0f / 4096.0f);

  // ctx_all = ctxp + mean * g3 -> out (complete, no later correction needed)
  float* op = out + (size_t)plane * N + nbase;
  #pragma unroll
  for(int q = 0; q < 4; q++){
    float4 g = *(const float4*)(g3p + q * 4);
    float4 r;
    r.x = fmaf(mean, g.x, ctxp[q*4+0]);
    r.y = fmaf(mean, g.y, ctxp[q*4+1]);
    r.z = fmaf(mean, g.z, ctxp[q*4+2]);
    r.w = fmaf(mean, g.w, ctxp[q*4+3]);
    *(float4*)(op + q * 4) = r;
  }
}

// ---------------- logits[b,n] = sum_c kw[c]*P[b,c,n] + kb ----------
__global__ __launch_bounds__(256)
void k_logits(const float* __restrict__ P, const float* __restrict__ key_w,
              const float* __restrict__ key_b, float* __restrict__ logits){
  __shared__ float kw[256];
  __shared__ float part[256];
  int tid = threadIdx.x;
  kw[tid] = key_w[tid];
  __syncthreads();
  int b = blockIdx.x >> 6;
  int n0 = (blockIdx.x & 63) * 64;
  int cpart = tid >> 6, px = tid & 63;
  const float* pp = P + ((size_t)(b * 256 + cpart * 64)) * N + n0 + px;
  float acc = 0.f;
  #pragma unroll 8
  for(int c = 0; c < 64; c++)
    acc = fmaf(kw[cpart * 64 + c], pp[(size_t)c * N], acc);
  part[tid] = acc;
  __syncthreads();
  if(tid < 64){
    float l = part[tid] + part[64 + tid] + part[128 + tid] + part[192 + tid];
    logits[b * N + n0 + tid] = l + key_b[0];
  }
}

// ---------------- softmax over N per batch ----------
__global__ __launch_bounds__(256)
void k_softmax(float* __restrict__ kbuf){
  __shared__ float red[256];
  int b = blockIdx.x, tid = threadIdx.x;
  float v[16];
  float m = -1e30f;
  #pragma unroll
  for(int i = 0; i < 16; i++){
    v[i] = kbuf[b * N + tid + i * 256];
    m = fmaxf(m, v[i]);
  }
  red[tid] = m; __syncthreads();
  for(int s = 128; s > 0; s >>= 1){
    if(tid < s) red[tid] = fmaxf(red[tid], red[tid + s]);
    __syncthreads();
  }
  m = red[0]; __syncthreads();
  float ssum = 0.f;
  #pragma unroll
  for(int i = 0; i < 16; i++){ v[i] = expf(v[i] - m); ssum += v[i]; }
  red[tid] = ssum; __syncthreads();
  for(int s = 128; s > 0; s >>= 1){
    if(tid < s) red[tid] += red[tid + s];
    __syncthreads();
  }
  float inv = 1.0f / red[0];
  #pragma unroll
  for(int i = 0; i < 16; i++)
    kbuf[b * N + tid + i * 256] = v[i] * inv;
}

// ---------------- qk[b,c] = sum_n P[b,c,n]*k[b,n] ----------
__global__ __launch_bounds__(256)
void k_qk(const float* __restrict__ P, const float* __restrict__ kbuf,
          float* __restrict__ qk){
  __shared__ float red[256];
  int plane = blockIdx.x, tid = threadIdx.x;
  int b = plane >> 8;
  const float* pp = P + (size_t)plane * N;
  const float* kp = kbuf + b * N;
  float acc = 0.f;
  #pragma unroll
  for(int i = 0; i < 16; i++){
    int n = tid + i * 256;
    acc = fmaf(pp[n], kp[n], acc);
  }
  red[tid] = acc; __syncthreads();
  for(int s = 128; s > 0; s >>= 1){
    if(tid < s) red[tid] += red[tid + s];
    __syncthreads();
  }
  if(tid == 0) qk[plane] = red[0];
}

// ---------------- v pipeline per batch: v1 -> LN -> relu -> v2 ----------
__global__ __launch_bounds__(256)
void k_v(const float* __restrict__ qk, const float* __restrict__ v1w,
         const float* __restrict__ v1b, const float* __restrict__ lnw,
         const float* __restrict__ lnb, const float* __restrict__ v2w,
         const float* __restrict__ v2b, float* __restrict__ vout){
  int b = blockIdx.x, tid = threadIdx.x;
  __shared__ float qs[256];
  __shared__ float part[256];
  __shared__ float v1s[16];
  __shared__ float vr[16];
  __shared__ float stats[2];
  qs[tid] = qk[b * 256 + tid];
  __syncthreads();
  int oc = tid >> 4, ln = tid & 15;
  float p = 0.f;
  #pragma unroll
  for(int j = 0; j < 16; j++){
    int cc = ln + j * 16;
    p = fmaf(v1w[oc * 256 + cc], qs[cc], p);
  }
  part[tid] = p;
  __syncthreads();
  if(tid < 16){
    float s = v1b[tid];
    for(int j = 0; j < 16; j++) s += part[tid * 16 + j];
    v1s[tid] = s;
  }
  __syncthreads();
  if(tid == 0){
    float mu = 0.f;
    for(int i = 0; i < 16; i++) mu += v1s[i];
    mu *= (1.f / 16.f);
    float var = 0.f;
    for(int i = 0; i < 16; i++){ float d = v1s[i] - mu; var += d * d; }
    var *= (1.f / 16.f);
    stats[0] = mu; stats[1] = rsqrtf(var + 1e-5f);
  }
  __syncthreads();
  if(tid < 16){
    float vv = (v1s[tid] - stats[0]) * stats[1] * lnw[tid] + lnb[tid];
    vr[tid] = fmaxf(vv, 0.f);
  }
  __syncthreads();
  float o = v2b[tid];
  #pragma unroll
  for(int j = 0; j < 16; j++) o = fmaf(v2w[tid * 16 + j], vr[j], o);
  vout[b * 256 + tid] = o;
}

// ---------------- out += vout (broadcast per plane) ----------
__global__ __launch_bounds__(256)
void k_final(float* __restrict__ out, const float* __restrict__ vout){
  int idx = blockIdx.x * 256 + threadIdx.x;   // float4 index
  int plane = idx >> 10;
  float4 p = *((float4*)out + idx);
  float vv = vout[plane];
  p.x += vv; p.y += vv; p.z += vv; p.w += vv;
  *((float4*)out + idx) = p;
}

extern "C" void kernel_launch(void* const* d_in, const int* in_sizes, int n_in,
                              void* d_out, int out_size, void* d_ws, size_t ws_size,
                              hipStream_t stream){
  const float* x      = (const float*)d_in[0];
  const float* conv_w = (const float*)d_in[1];
  const float* conv_b = (const float*)d_in[2];
  const float* fw3    = (const float*)d_in[3];
  const float* fw5    = (const float*)d_in[4];
  const float* fw7    = (const float*)d_in[5];
  const float* key_w  = (const float*)d_in[6];
  const float* key_b  = (const float*)d_in[7];
  const float* v1_w   = (const float*)d_in[8];
  const float* v1_b   = (const float*)d_in[9];
  const float* ln_w   = (const float*)d_in[10];
  const float* ln_b   = (const float*)d_in[11];
  const float* v2_w   = (const float*)d_in[12];
  const float* v2_b   = (const float*)d_in[13];
  float* out = (float*)d_out;
  float* ws  = (float*)d_ws;

  const size_t PL = (size_t)B * C * N;     // 16,777,216 floats
  float* ctx   = ws;                       // conv1 output, 256 ch
  float* gates = ws + PL;                  // B*4*N
  float* kbuf  = gates + (size_t)B * 4 * N;// B*N
  float* qkb   = kbuf + (size_t)B * N;     // B*C
  float* vout  = qkb + B * C;              // B*C

  // 1. conv1x1 -> ctx (256 ch) + gates (4 ch)
  k_conv1<<<dim3(256, 5), 256, 0, stream>>>(x, conv_w, conv_b, ctx, gates);
  // 2. fused dw3/dw5/dw7 chain + gating + global-mean term -> out = full ctx_all
  k_dwchain<<<B * C, 256, 0, stream>>>(ctx, fw3, fw5, fw7, gates, out);
  // 3. logits
  k_logits<<<1024, 256, 0, stream>>>(out, key_w, key_b, kbuf);
  // 4. softmax
  k_softmax<<<B, 256, 0, stream>>>(kbuf);
  // 5. qk
  k_qk<<<B * C, 256, 0, stream>>>(out, kbuf, qkb);
  // 6. v pipeline
  k_v<<<B, 256, 0, stream>>>(qkb, v1_w, v1_b, ln_w, ln_b, v2_w, v2_b, vout);
  // 7. final: out += v broadcast
  k_final<<<16384, 256, 0, stream>>>(out, vout);
}

// Round 3
// 425.901 us; speedup vs baseline: 2.1152x; 1.3516x over previous
//
#include <hip/hip_runtime.h>

#define DEVFN __device__ __forceinline__

constexpr int B  = 16;
constexpr int C  = 256;
constexpr int N  = 64 * 64;     // 4096
constexpr int O1 = C + 4;       // 260

typedef __attribute__((ext_vector_type(8)))  short bf16x8;
typedef __attribute__((ext_vector_type(16))) float f32x16;

DEVFN float gelu_exact(float x){
  return 0.5f * x * (1.0f + erff(x * 0.7071067811865476f));
}

DEVFN short f2bf(float f){
  union { float f; unsigned u; } p; p.f = f;
  unsigned r = p.u + 0x7fffu + ((p.u >> 16) & 1u);   // RNE
  return (short)(r >> 16);
}

// ---------------- K1: conv1x1 as bf16 MFMA GEMM ----------
// t[o,p] = sum_c W[o,c] x[c,p] + b[o];  M=260(pad 320), N=65536, K=256.
// Block: 64 o x 64 px, 4 waves each one 32x32 tile via mfma_f32_32x32x16_bf16.
// K chunked by 128; LDS fragment-major [kgroup][row][8bf16] -> all LDS ops
// are contiguous b128 (conflict-free).
__global__ __launch_bounds__(256, 4)
void k_conv1_mfma(const float* __restrict__ x, const float* __restrict__ w,
                  const float* __restrict__ bias, float* __restrict__ ctx,
                  float* __restrict__ gates){
  __shared__ __align__(16) short wlds[16 * 64 * 8];   // 16KB: [kg][m][8]
  __shared__ __align__(16) short xlds[16 * 64 * 8];   // 16KB: [kg][n][8]
  const int tid  = threadIdx.x;
  const int wv   = tid >> 6;
  const int lane = tid & 63;
  const int l31  = lane & 31;
  const int lhi  = lane >> 5;          // 0/1: selects k-half of fragment
  const int oBase = blockIdx.y * 64;
  const int pg0   = blockIdx.x * 64;
  const int b  = pg0 >> 12;
  const int n0 = pg0 & 4095;
  const int mw = (wv >> 1) * 32;       // wave tile offsets in block
  const int nw = (wv & 1) * 32;

  f32x16 acc;
  #pragma unroll
  for(int r = 0; r < 16; r++) acc[r] = 0.f;

  const int rstage = tid & 63;         // staging row handled by this thread
  const int kg0    = (tid >> 6) * 4;   // 4 kgroups per thread per chunk

  for(int kc = 0; kc < 256; kc += 128){
    __syncthreads();
    // ---- stage W chunk: [kg][m][8 bf16], reads are 32B-contig per thread
    {
      const int o = oBase + rstage;
      const float* wp = w + o * 256 + kc;
      #pragma unroll
      for(int t = 0; t < 4; t++){
        const int kg = kg0 + t;
        bf16x8 v;
        if(o < O1){
          const float4 f0 = *(const float4*)(wp + kg * 8);
          const float4 f1 = *(const float4*)(wp + kg * 8 + 4);
          v[0] = f2bf(f0.x); v[1] = f2bf(f0.y); v[2] = f2bf(f0.z); v[3] = f2bf(f0.w);
          v[4] = f2bf(f1.x); v[5] = f2bf(f1.y); v[6] = f2bf(f1.z); v[7] = f2bf(f1.w);
        } else {
          #pragma unroll
          for(int j = 0; j < 8; j++) v[j] = 0;
        }
        *(bf16x8*)&wlds[(kg * 64 + rstage) * 8] = v;
      }
    }
    // ---- stage X chunk: lane-coalesced dword reads (lanes span n), b128 LDS writes
    {
      const float* xp = x + (size_t)b * C * N + (size_t)kc * N + n0 + rstage;
      #pragma unroll
      for(int t = 0; t < 4; t++){
        const int kg = kg0 + t;
        float f[8];
        #pragma unroll
        for(int j = 0; j < 8; j++) f[j] = xp[(size_t)(kg * 8 + j) * N];
        bf16x8 v;
        #pragma unroll
        for(int j = 0; j < 8; j++) v[j] = f2bf(f[j]);
        *(bf16x8*)&xlds[(kg * 64 + rstage) * 8] = v;
      }
    }
    __syncthreads();
    // ---- 8 k-steps of 32x32x16
    #pragma unroll
    for(int ks = 0; ks < 8; ks++){
      const int kg = ks * 2 + lhi;
      bf16x8 af = *(const bf16x8*)&wlds[(kg * 64 + mw + l31) * 8];
      bf16x8 bfr = *(const bf16x8*)&xlds[(kg * 64 + nw + l31) * 8];
      acc = __builtin_amdgcn_mfma_f32_32x32x16_bf16(af, bfr, acc, 0, 0, 0);
    }
  }

  // ---- epilogue: C/D layout col=lane&31, row=(r&3)+8*(r>>2)+4*(lane>>5)
  const int n = n0 + nw + l31;
  #pragma unroll
  for(int r = 0; r < 16; r++){
    const int row = (r & 3) + 8 * (r >> 2) + 4 * lhi;
    const int o = oBase + mw + row;
    if(o >= O1) continue;
    const float v = acc[r] + bias[o];
    if(o < 256)
      ctx[((size_t)(b * 256 + o)) * N + n] = v;
    else
      gates[((size_t)(b * 4 + (o - 256))) * N + n] = v;
  }
}

// ---------------- fused depthwise chain ----------
constexpr int DSTR = 76;
constexpr int DROWS = 70;

template<int K>
DEVFN void dw_conv(const float* __restrict__ src, const float* __restrict__ wk,
                   int h, int w0, float* val){
  constexpr int R = K / 2;
  float acc[16];
  #pragma unroll
  for(int p = 0; p < 16; p++) acc[p] = 0.f;
  #pragma unroll
  for(int ky = 0; ky < K; ky++){
    const float* rp = &src[(h + 3 - R + ky) * DSTR + w0];
    float rowreg[24];
    #pragma unroll
    for(int q = 0; q < 6; q++){
      float4 v4 = *(const float4*)(rp + q * 4);
      rowreg[q*4+0] = v4.x; rowreg[q*4+1] = v4.y;
      rowreg[q*4+2] = v4.z; rowreg[q*4+3] = v4.w;
    }
    #pragma unroll
    for(int kx = 0; kx < K; kx++){
      float wv = wk[ky * K + kx];
      #pragma unroll
      for(int p = 0; p < 16; p++)
        acc[p] = fmaf(rowreg[p + kx + 4 - R], wv, acc[p]);
    }
  }
  #pragma unroll
  for(int p = 0; p < 16; p++) val[p] = gelu_exact(acc[p]);
}

__global__ __launch_bounds__(256)
void k_dwchain(const float* __restrict__ in, const float* __restrict__ fw3,
               const float* __restrict__ fw5, const float* __restrict__ fw7,
               const float* __restrict__ gates, float* __restrict__ out){
  __shared__ __align__(16) float bufA[DROWS * DSTR];
  __shared__ __align__(16) float bufB[DROWS * DSTR];
  __shared__ float wk3[9], wk5[25], wk7[49];
  __shared__ float red[256];
  const int tid = threadIdx.x;
  const int plane = blockIdx.x;
  const int b = plane >> 8;
  const int c = plane & 255;
  const float* ip = in + (size_t)plane * N;

  for(int idx = tid; idx < DROWS * DSTR; idx += 256){ bufA[idx] = 0.f; bufB[idx] = 0.f; }
  if(tid < 9)  wk3[tid] = fw3[c * 9 + tid];
  if(tid < 25) wk5[tid] = fw5[c * 25 + tid];
  if(tid < 49) wk7[tid] = fw7[c * 49 + tid];
  __syncthreads();
  const float4* ip4 = (const float4*)ip;
  #pragma unroll
  for(int i = 0; i < 4; i++){
    int idx4 = tid + i * 256;
    int gy = idx4 >> 4, gx4 = (idx4 & 15) * 4;
    *(float4*)&bufA[(gy + 3) * DSTR + gx4 + 4] = ip4[idx4];
  }
  __syncthreads();

  const int h  = tid >> 2;
  const int w0 = (tid & 3) * 16;
  const int nbase = h * 64 + w0;
  const float* g0p = gates + ((size_t)(b * 4 + 0)) * N + nbase;
  const float* g1p = gates + ((size_t)(b * 4 + 1)) * N + nbase;
  const float* g2p = gates + ((size_t)(b * 4 + 2)) * N + nbase;
  const float* g3p = gates + ((size_t)(b * 4 + 3)) * N + nbase;

  float ctxp[16];
  #pragma unroll
  for(int p = 0; p < 16; p++) ctxp[p] = 0.f;
  float val[16];

  dw_conv<3>(bufA, wk3, h, w0, val);
  #pragma unroll
  for(int q = 0; q < 4; q++){
    float4 g = *(const float4*)(g0p + q * 4);
    ctxp[q*4+0] = fmaf(val[q*4+0], g.x, ctxp[q*4+0]);
    ctxp[q*4+1] = fmaf(val[q*4+1], g.y, ctxp[q*4+1]);
    ctxp[q*4+2] = fmaf(val[q*4+2], g.z, ctxp[q*4+2]);
    ctxp[q*4+3] = fmaf(val[q*4+3], g.w, ctxp[q*4+3]);
    float4 vv; vv.x = val[q*4+0]; vv.y = val[q*4+1]; vv.z = val[q*4+2]; vv.w = val[q*4+3];
    *(float4*)&bufB[(h + 3) * DSTR + w0 + 4 + q * 4] = vv;
  }
  __syncthreads();

  dw_conv<5>(bufB, wk5, h, w0, val);
  #pragma unroll
  for(int q = 0; q < 4; q++){
    float4 g = *(const float4*)(g1p + q * 4);
    ctxp[q*4+0] = fmaf(val[q*4+0], g.x, ctxp[q*4+0]);
    ctxp[q*4+1] = fmaf(val[q*4+1], g.y, ctxp[q*4+1]);
    ctxp[q*4+2] = fmaf(val[q*4+2], g.z, ctxp[q*4+2]);
    ctxp[q*4+3] = fmaf(val[q*4+3], g.w, ctxp[q*4+3]);
    float4 vv; vv.x = val[q*4+0]; vv.y = val[q*4+1]; vv.z = val[q*4+2]; vv.w = val[q*4+3];
    *(float4*)&bufA[(h + 3) * DSTR + w0 + 4 + q * 4] = vv;
  }
  __syncthreads();

  dw_conv<7>(bufA, wk7, h, w0, val);
  float lsum = 0.f;
  #pragma unroll
  for(int q = 0; q < 4; q++){
    float4 g = *(const float4*)(g2p + q * 4);
    ctxp[q*4+0] = fmaf(val[q*4+0], g.x, ctxp[q*4+0]);
    ctxp[q*4+1] = fmaf(val[q*4+1], g.y, ctxp[q*4+1]);
    ctxp[q*4+2] = fmaf(val[q*4+2], g.z, ctxp[q*4+2]);
    ctxp[q*4+3] = fmaf(val[q*4+3], g.w, ctxp[q*4+3]);
    lsum += val[q*4+0] + val[q*4+1] + val[q*4+2] + val[q*4+3];
  }
  red[tid] = lsum;
  __syncthreads();
  for(int s = 128; s > 0; s >>= 1){
    if(tid < s) red[tid] += red[tid + s];
    __syncthreads();
  }
  const float mean = red[0] * (1.0f / 4096.0f);

  float* op = out + (size_t)plane * N + nbase;
  #pragma unroll
  for(int q = 0; q < 4; q++){
    float4 g = *(const float4*)(g3p + q * 4);
    float4 r;
    r.x = fmaf(mean, g.x, ctxp[q*4+0]);
    r.y = fmaf(mean, g.y, ctxp[q*4+1]);
    r.z = fmaf(mean, g.z, ctxp[q*4+2]);
    r.w = fmaf(mean, g.w, ctxp[q*4+3]);
    *(float4*)(op + q * 4) = r;
  }
}

// ---------------- logits[b,n] = sum_c kw[c]*P[b,c,n] + kb ----------
__global__ __launch_bounds__(256)
void k_logits(const float* __restrict__ P, const float* __restrict__ key_w,
              const float* __restrict__ key_b, float* __restrict__ logits){
  __shared__ float kw[256];
  __shared__ float part[256];
  int tid = threadIdx.x;
  kw[tid] = key_w[tid];
  __syncthreads();
  int b = blockIdx.x >> 6;
  int n0 = (blockIdx.x & 63) * 64;
  int cpart = tid >> 6, px = tid & 63;
  const float* pp = P + ((size_t)(b * 256 + cpart * 64)) * N + n0 + px;
  float acc = 0.f;
  #pragma unroll 8
  for(int c = 0; c < 64; c++)
    acc = fmaf(kw[cpart * 64 + c], pp[(size_t)c * N], acc);
  part[tid] = acc;
  __syncthreads();
  if(tid < 64){
    float l = part[tid] + part[64 + tid] + part[128 + tid] + part[192 + tid];
    logits[b * N + n0 + tid] = l + key_b[0];
  }
}

// ---------------- softmax over N per batch ----------
__global__ __launch_bounds__(256)
void k_softmax(float* __restrict__ kbuf){
  __shared__ float red[256];
  int b = blockIdx.x, tid = threadIdx.x;
  float v[16];
  float m = -1e30f;
  #pragma unroll
  for(int i = 0; i < 16; i++){
    v[i] = kbuf[b * N + tid + i * 256];
    m = fmaxf(m, v[i]);
  }
  red[tid] = m; __syncthreads();
  for(int s = 128; s > 0; s >>= 1){
    if(tid < s) red[tid] = fmaxf(red[tid], red[tid + s]);
    __syncthreads();
  }
  m = red[0]; __syncthreads();
  float ssum = 0.f;
  #pragma unroll
  for(int i = 0; i < 16; i++){ v[i] = expf(v[i] - m); ssum += v[i]; }
  red[tid] = ssum; __syncthreads();
  for(int s = 128; s > 0; s >>= 1){
    if(tid < s) red[tid] += red[tid + s];
    __syncthreads();
  }
  float inv = 1.0f / red[0];
  #pragma unroll
  for(int i = 0; i < 16; i++)
    kbuf[b * N + tid + i * 256] = v[i] * inv;
}

// ---------------- qk[b,c] = sum_n P[b,c,n]*k[b,n] ----------
__global__ __launch_bounds__(256)
void k_qk(const float* __restrict__ P, const float* __restrict__ kbuf,
          float* __restrict__ qk){
  __shared__ float red[256];
  int plane = blockIdx.x, tid = threadIdx.x;
  int b = plane >> 8;
  const float* pp = P + (size_t)plane * N;
  const float* kp = kbuf + b * N;
  float acc = 0.f;
  #pragma unroll
  for(int i = 0; i < 16; i++){
    int n = tid + i * 256;
    acc = fmaf(pp[n], kp[n], acc);
  }
  red[tid] = acc; __syncthreads();
  for(int s = 128; s > 0; s >>= 1){
    if(tid < s) red[tid] += red[tid + s];
    __syncthreads();
  }
  if(tid == 0) qk[plane] = red[0];
}

// ---------------- v pipeline per batch: v1 -> LN -> relu -> v2 ----------
__global__ __launch_bounds__(256)
void k_v(const float* __restrict__ qk, const float* __restrict__ v1w,
         const float* __restrict__ v1b, const float* __restrict__ lnw,
         const float* __restrict__ lnb, const float* __restrict__ v2w,
         const float* __restrict__ v2b, float* __restrict__ vout){
  int b = blockIdx.x, tid = threadIdx.x;
  __shared__ float qs[256];
  __shared__ float part[256];
  __shared__ float v1s[16];
  __shared__ float vr[16];
  __shared__ float stats[2];
  qs[tid] = qk[b * 256 + tid];
  __syncthreads();
  int oc = tid >> 4, ln = tid & 15;
  float p = 0.f;
  #pragma unroll
  for(int j = 0; j < 16; j++){
    int cc = ln + j * 16;
    p = fmaf(v1w[oc * 256 + cc], qs[cc], p);
  }
  part[tid] = p;
  __syncthreads();
  if(tid < 16){
    float s = v1b[tid];
    for(int j = 0; j < 16; j++) s += part[tid * 16 + j];
    v1s[tid] = s;
  }
  __syncthreads();
  if(tid == 0){
    float mu = 0.f;
    for(int i = 0; i < 16; i++) mu += v1s[i];
    mu *= (1.f / 16.f);
    float var = 0.f;
    for(int i = 0; i < 16; i++){ float d = v1s[i] - mu; var += d * d; }
    var *= (1.f / 16.f);
    stats[0] = mu; stats[1] = rsqrtf(var + 1e-5f);
  }
  __syncthreads();
  if(tid < 16){
    float vv = (v1s[tid] - stats[0]) * stats[1] * lnw[tid] + lnb[tid];
    vr[tid] = fmaxf(vv, 0.f);
  }
  __syncthreads();
  float o = v2b[tid];
  #pragma unroll
  for(int j = 0; j < 16; j++) o = fmaf(v2w[tid * 16 + j], vr[j], o);
  vout[b * 256 + tid] = o;
}

// ---------------- out += vout (broadcast per plane) ----------
__global__ __launch_bounds__(256)
void k_final(float* __restrict__ out, const float* __restrict__ vout){
  int idx = blockIdx.x * 256 + threadIdx.x;   // float4 index
  int plane = idx >> 10;
  float4 p = *((float4*)out + idx);
  float vv = vout[plane];
  p.x += vv; p.y += vv; p.z += vv; p.w += vv;
  *((float4*)out + idx) = p;
}

extern "C" void kernel_launch(void* const* d_in, const int* in_sizes, int n_in,
                              void* d_out, int out_size, void* d_ws, size_t ws_size,
                              hipStream_t stream){
  const float* x      = (const float*)d_in[0];
  const float* conv_w = (const float*)d_in[1];
  const float* conv_b = (const float*)d_in[2];
  const float* fw3    = (const float*)d_in[3];
  const float* fw5    = (const float*)d_in[4];
  const float* fw7    = (const float*)d_in[5];
  const float* key_w  = (const float*)d_in[6];
  const float* key_b  = (const float*)d_in[7];
  const float* v1_w   = (const float*)d_in[8];
  const float* v1_b   = (const float*)d_in[9];
  const float* ln_w   = (const float*)d_in[10];
  const float* ln_b   = (const float*)d_in[11];
  const float* v2_w   = (const float*)d_in[12];
  const float* v2_b   = (const float*)d_in[13];
  float* out = (float*)d_out;
  float* ws  = (float*)d_ws;

  const size_t PL = (size_t)B * C * N;
  float* ctx   = ws;
  float* gates = ws + PL;
  float* kbuf  = gates + (size_t)B * 4 * N;
  float* qkb   = kbuf + (size_t)B * N;
  float* vout  = qkb + B * C;

  // 1. conv1x1 via bf16 MFMA -> ctx (256 ch) + gates (4 ch)
  k_conv1_mfma<<<dim3(1024, 5), 256, 0, stream>>>(x, conv_w, conv_b, ctx, gates);
  // 2. fused dw3/dw5/dw7 chain + gating + global-mean term -> out = full ctx_all
  k_dwchain<<<B * C, 256, 0, stream>>>(ctx, fw3, fw5, fw7, gates, out);
  // 3. logits
  k_logits<<<1024, 256, 0, stream>>>(out, key_w, key_b, kbuf);
  // 4. softmax
  k_softmax<<<B, 256, 0, stream>>>(kbuf);
  // 5. qk
  k_qk<<<B * C, 256, 0, stream>>>(out, kbuf, qkb);
  // 6. v pipeline
  k_v<<<B, 256, 0, stream>>>(qkb, v1_w, v1_b, ln_w, ln_b, v2_w, v2_b, vout);
  // 7. final: out += v broadcast
  k_final<<<16384, 256, 0, stream>>>(out, vout);
}

// Round 4
// 312.309 us; speedup vs baseline: 2.8846x; 1.3637x over previous
//
#include <hip/hip_runtime.h>

#define DEVFN __device__ __forceinline__

constexpr int B  = 16;
constexpr int C  = 256;
constexpr int N  = 64 * 64;     // 4096
constexpr int O1 = C + 4;       // 260

typedef __attribute__((ext_vector_type(8)))  short bf16x8;
typedef __attribute__((ext_vector_type(4)))  short bf16x4;
typedef __attribute__((ext_vector_type(16))) float f32x16;
typedef unsigned short ushort_t;

DEVFN short f2bf(float f){
  union { float f; unsigned u; } p; p.f = f;
  unsigned r = p.u + 0x7fffu + ((p.u >> 16) & 1u);   // RNE
  return (short)(r >> 16);
}
DEVFN float lo2f(unsigned u){ union{unsigned u; float f;} p; p.u = u << 16; return p.f; }
DEVFN float hi2f(unsigned u){ union{unsigned u; float f;} p; p.u = u & 0xffff0000u; return p.f; }

// tanh-form gelu: x * sigmoid(1.5957691*(x + 0.044715 x^3)); max err ~5e-4
DEVFN float gelu_fast(float x){
  float y = 1.5957691216f * fmaf(0.044715f * x * x, x, x);
  return x / (1.0f + __expf(-y));
}

// ---------------- K1: conv1x1 as bf16 MFMA GEMM (ctx out in bf16) ----------
__global__ __launch_bounds__(256, 4)
void k_conv1_mfma(const float* __restrict__ x, const float* __restrict__ w,
                  const float* __restrict__ bias, ushort_t* __restrict__ ctxb,
                  float* __restrict__ gates){
  __shared__ __align__(16) short wlds[16 * 64 * 8];   // 16KB: [kg][m][8]
  __shared__ __align__(16) short xlds[16 * 64 * 8];   // 16KB: [kg][n][8]
  const int tid  = threadIdx.x;
  const int wv   = tid >> 6;
  const int lane = tid & 63;
  const int l31  = lane & 31;
  const int lhi  = lane >> 5;
  const int oBase = blockIdx.y * 64;
  const int pg0   = blockIdx.x * 64;
  const int b  = pg0 >> 12;
  const int n0 = pg0 & 4095;
  const int mw = (wv >> 1) * 32;
  const int nw = (wv & 1) * 32;

  f32x16 acc;
  #pragma unroll
  for(int r = 0; r < 16; r++) acc[r] = 0.f;

  const int rstage = tid & 63;
  const int kg0    = (tid >> 6) * 4;

  for(int kc = 0; kc < 256; kc += 128){
    __syncthreads();
    {
      const int o = oBase + rstage;
      const float* wp = w + o * 256 + kc;
      #pragma unroll
      for(int t = 0; t < 4; t++){
        const int kg = kg0 + t;
        bf16x8 v;
        if(o < O1){
          const float4 f0 = *(const float4*)(wp + kg * 8);
          const float4 f1 = *(const float4*)(wp + kg * 8 + 4);
          v[0] = f2bf(f0.x); v[1] = f2bf(f0.y); v[2] = f2bf(f0.z); v[3] = f2bf(f0.w);
          v[4] = f2bf(f1.x); v[5] = f2bf(f1.y); v[6] = f2bf(f1.z); v[7] = f2bf(f1.w);
        } else {
          #pragma unroll
          for(int j = 0; j < 8; j++) v[j] = 0;
        }
        *(bf16x8*)&wlds[(kg * 64 + rstage) * 8] = v;
      }
    }
    {
      const float* xp = x + (size_t)b * C * N + (size_t)kc * N + n0 + rstage;
      #pragma unroll
      for(int t = 0; t < 4; t++){
        const int kg = kg0 + t;
        float f[8];
        #pragma unroll
        for(int j = 0; j < 8; j++) f[j] = xp[(size_t)(kg * 8 + j) * N];
        bf16x8 v;
        #pragma unroll
        for(int j = 0; j < 8; j++) v[j] = f2bf(f[j]);
        *(bf16x8*)&xlds[(kg * 64 + rstage) * 8] = v;
      }
    }
    __syncthreads();
    #pragma unroll
    for(int ks = 0; ks < 8; ks++){
      const int kg = ks * 2 + lhi;
      bf16x8 af = *(const bf16x8*)&wlds[(kg * 64 + mw + l31) * 8];
      bf16x8 bfr = *(const bf16x8*)&xlds[(kg * 64 + nw + l31) * 8];
      acc = __builtin_amdgcn_mfma_f32_32x32x16_bf16(af, bfr, acc, 0, 0, 0);
    }
  }

  const int n = n0 + nw + l31;
  #pragma unroll
  for(int r = 0; r < 16; r++){
    const int row = (r & 3) + 8 * (r >> 2) + 4 * lhi;
    const int o = oBase + mw + row;
    if(o >= O1) continue;
    const float v = acc[r] + bias[o];
    if(o < 256)
      ctxb[((size_t)(b * 256 + o)) * N + n] = (ushort_t)f2bf(v);
    else
      gates[((size_t)(b * 4 + (o - 256))) * N + n] = v;
  }
}

// ---------------- fused depthwise chain v2 ----------
// 512 threads: thread = (row h, 8-wide col seg). bf16 LDS tiles, no row halos
// (predicated skip), col halo +-4 zeroed once. Weights via uniform scalar loads.
constexpr int SSTR = 72;   // shorts per row: 4 + 64 + 4; 144B = 16B-aligned rows

DEVFN void unpack16(const short* p, float* wnd){
  uint4 a = *(const uint4*)p;
  uint4 b = *(const uint4*)(p + 8);
  unsigned ua[8] = {a.x, a.y, a.z, a.w, b.x, b.y, b.z, b.w};
  #pragma unroll
  for(int d = 0; d < 8; d++){ wnd[2*d] = lo2f(ua[d]); wnd[2*d+1] = hi2f(ua[d]); }
}

template<int K>
DEVFN void dw_stage(const short* src, const float* __restrict__ fw, int c,
                    int h, int w0, float* val){
  constexpr int R = K / 2;
  float acc[8];
  #pragma unroll
  for(int i = 0; i < 8; i++) acc[i] = 0.f;
  #pragma unroll
  for(int ky = 0; ky < K; ky++){
    const int r = h + ky - R;
    if((unsigned)r < 64u){
      float wnd[16];
      unpack16(&src[r * SSTR + w0], wnd);       // covers cols [w0-4, w0+12)
      #pragma unroll
      for(int kx = 0; kx < K; kx++){
        const float wv = fw[c * K * K + ky * K + kx];   // uniform -> SGPR
        #pragma unroll
        for(int i = 0; i < 8; i++)
          acc[i] = fmaf(wnd[i + kx + 4 - R], wv, acc[i]);
      }
    }
  }
  #pragma unroll
  for(int i = 0; i < 8; i++) val[i] = gelu_fast(acc[i]);
}

DEVFN void store_row(short* dst, int h, int w0, const float* val){
  bf16x4 lo, hi;
  #pragma unroll
  for(int i = 0; i < 4; i++){ lo[i] = f2bf(val[i]); hi[i] = f2bf(val[i + 4]); }
  *(bf16x4*)&dst[h * SSTR + w0 + 4] = lo;   // 8B-aligned
  *(bf16x4*)&dst[h * SSTR + w0 + 8] = hi;
}

__global__ __launch_bounds__(512, 6)
void k_dwchain(const ushort_t* __restrict__ ctxb, const float* __restrict__ fw3,
               const float* __restrict__ fw5, const float* __restrict__ fw7,
               const float* __restrict__ gates, float* __restrict__ out){
  __shared__ __align__(16) short bufA[64 * SSTR];
  __shared__ __align__(16) short bufB[64 * SSTR];
  __shared__ float red[512];
  const int tid = threadIdx.x;
  const int plane = blockIdx.x;
  const int b = plane >> 8;
  const int c = plane & 255;
  const int h  = tid >> 3;
  const int w0 = (tid & 7) * 8;
  const int nbase = h * 64 + w0;

  // zero col halos (rows have no stored halo)
  if(tid < 64){
    bf16x4 z = {0, 0, 0, 0};
    *(bf16x4*)&bufA[tid * SSTR] = z;  *(bf16x4*)&bufA[tid * SSTR + 68] = z;
    *(bf16x4*)&bufB[tid * SSTR] = z;  *(bf16x4*)&bufB[tid * SSTR + 68] = z;
  }
  // stage input plane (bf16 global -> LDS), thread owns its own (h,w0) seg
  {
    bf16x8 iv = *(const bf16x8*)((const short*)ctxb + (size_t)plane * N + tid * 8);
    bf16x4 lo, hi;
    #pragma unroll
    for(int j = 0; j < 4; j++){ lo[j] = iv[j]; hi[j] = iv[j + 4]; }
    *(bf16x4*)&bufA[h * SSTR + w0 + 4] = lo;
    *(bf16x4*)&bufA[h * SSTR + w0 + 8] = hi;
  }
  __syncthreads();

  float ctxp[8];
  #pragma unroll
  for(int i = 0; i < 8; i++) ctxp[i] = 0.f;
  float val[8];

  // stage 1: dw3 A->B
  dw_stage<3>(bufA, fw3, c, h, w0, val);
  {
    const float* gp = gates + ((size_t)(b * 4 + 0)) * N + nbase;
    float4 ga = *(const float4*)gp, gb = *(const float4*)(gp + 4);
    ctxp[0] = fmaf(val[0], ga.x, ctxp[0]); ctxp[1] = fmaf(val[1], ga.y, ctxp[1]);
    ctxp[2] = fmaf(val[2], ga.z, ctxp[2]); ctxp[3] = fmaf(val[3], ga.w, ctxp[3]);
    ctxp[4] = fmaf(val[4], gb.x, ctxp[4]); ctxp[5] = fmaf(val[5], gb.y, ctxp[5]);
    ctxp[6] = fmaf(val[6], gb.z, ctxp[6]); ctxp[7] = fmaf(val[7], gb.w, ctxp[7]);
    store_row(bufB, h, w0, val);
  }
  __syncthreads();

  // stage 2: dw5 B->A
  dw_stage<5>(bufB, fw5, c, h, w0, val);
  {
    const float* gp = gates + ((size_t)(b * 4 + 1)) * N + nbase;
    float4 ga = *(const float4*)gp, gb = *(const float4*)(gp + 4);
    ctxp[0] = fmaf(val[0], ga.x, ctxp[0]); ctxp[1] = fmaf(val[1], ga.y, ctxp[1]);
    ctxp[2] = fmaf(val[2], ga.z, ctxp[2]); ctxp[3] = fmaf(val[3], ga.w, ctxp[3]);
    ctxp[4] = fmaf(val[4], gb.x, ctxp[4]); ctxp[5] = fmaf(val[5], gb.y, ctxp[5]);
    ctxp[6] = fmaf(val[6], gb.z, ctxp[6]); ctxp[7] = fmaf(val[7], gb.w, ctxp[7]);
    store_row(bufA, h, w0, val);
  }
  __syncthreads();

  // stage 3: dw7 A->regs; plane mean of gelu output
  dw_stage<7>(bufA, fw7, c, h, w0, val);
  float lsum = 0.f;
  {
    const float* gp = gates + ((size_t)(b * 4 + 2)) * N + nbase;
    float4 ga = *(const float4*)gp, gb = *(const float4*)(gp + 4);
    ctxp[0] = fmaf(val[0], ga.x, ctxp[0]); ctxp[1] = fmaf(val[1], ga.y, ctxp[1]);
    ctxp[2] = fmaf(val[2], ga.z, ctxp[2]); ctxp[3] = fmaf(val[3], ga.w, ctxp[3]);
    ctxp[4] = fmaf(val[4], gb.x, ctxp[4]); ctxp[5] = fmaf(val[5], gb.y, ctxp[5]);
    ctxp[6] = fmaf(val[6], gb.z, ctxp[6]); ctxp[7] = fmaf(val[7], gb.w, ctxp[7]);
    #pragma unroll
    for(int i = 0; i < 8; i++) lsum += val[i];
  }
  red[tid] = lsum;
  __syncthreads();
  for(int s = 256; s > 0; s >>= 1){
    if(tid < s) red[tid] += red[tid + s];
    __syncthreads();
  }
  const float mean = red[0] * (1.0f / 4096.0f);

  // out = ctxp + mean*g3
  {
    const float* gp = gates + ((size_t)(b * 4 + 3)) * N + nbase;
    float4 ga = *(const float4*)gp, gb = *(const float4*)(gp + 4);
    float4 o0, o1;
    o0.x = fmaf(mean, ga.x, ctxp[0]); o0.y = fmaf(mean, ga.y, ctxp[1]);
    o0.z = fmaf(mean, ga.z, ctxp[2]); o0.w = fmaf(mean, ga.w, ctxp[3]);
    o1.x = fmaf(mean, gb.x, ctxp[4]); o1.y = fmaf(mean, gb.y, ctxp[5]);
    o1.z = fmaf(mean, gb.z, ctxp[6]); o1.w = fmaf(mean, gb.w, ctxp[7]);
    float* op = out + (size_t)plane * N + nbase;
    *(float4*)op = o0;
    *(float4*)(op + 4) = o1;
  }
}

// ---------------- logits[b,n] = sum_c kw[c]*P[b,c,n] + kb ----------
__global__ __launch_bounds__(256)
void k_logits(const float* __restrict__ P, const float* __restrict__ key_w,
              const float* __restrict__ key_b, float* __restrict__ logits){
  __shared__ float kw[256];
  __shared__ float part[256];
  int tid = threadIdx.x;
  kw[tid] = key_w[tid];
  __syncthreads();
  int b = blockIdx.x >> 6;
  int n0 = (blockIdx.x & 63) * 64;
  int cpart = tid >> 6, px = tid & 63;
  const float* pp = P + ((size_t)(b * 256 + cpart * 64)) * N + n0 + px;
  float acc = 0.f;
  #pragma unroll 8
  for(int c = 0; c < 64; c++)
    acc = fmaf(kw[cpart * 64 + c], pp[(size_t)c * N], acc);
  part[tid] = acc;
  __syncthreads();
  if(tid < 64){
    float l = part[tid] + part[64 + tid] + part[128 + tid] + part[192 + tid];
    logits[b * N + n0 + tid] = l + key_b[0];
  }
}

// ---------------- softmax over N per batch ----------
__global__ __launch_bounds__(256)
void k_softmax(float* __restrict__ kbuf){
  __shared__ float red[256];
  int b = blockIdx.x, tid = threadIdx.x;
  float v[16];
  float m = -1e30f;
  #pragma unroll
  for(int i = 0; i < 16; i++){
    v[i] = kbuf[b * N + tid + i * 256];
    m = fmaxf(m, v[i]);
  }
  red[tid] = m; __syncthreads();
  for(int s = 128; s > 0; s >>= 1){
    if(tid < s) red[tid] = fmaxf(red[tid], red[tid + s]);
    __syncthreads();
  }
  m = red[0]; __syncthreads();
  float ssum = 0.f;
  #pragma unroll
  for(int i = 0; i < 16; i++){ v[i] = __expf(v[i] - m); ssum += v[i]; }
  red[tid] = ssum; __syncthreads();
  for(int s = 128; s > 0; s >>= 1){
    if(tid < s) red[tid] += red[tid + s];
    __syncthreads();
  }
  float inv = 1.0f / red[0];
  #pragma unroll
  for(int i = 0; i < 16; i++)
    kbuf[b * N + tid + i * 256] = v[i] * inv;
}

// ---------------- qk[b,c] = sum_n P[b,c,n]*k[b,n] ----------
__global__ __launch_bounds__(256)
void k_qk(const float* __restrict__ P, const float* __restrict__ kbuf,
          float* __restrict__ qk){
  __shared__ float red[256];
  int plane = blockIdx.x, tid = threadIdx.x;
  int b = plane >> 8;
  const float* pp = P + (size_t)plane * N;
  const float* kp = kbuf + b * N;
  float acc = 0.f;
  #pragma unroll
  for(int i = 0; i < 16; i++){
    int n = tid + i * 256;
    acc = fmaf(pp[n], kp[n], acc);
  }
  red[tid] = acc; __syncthreads();
  for(int s = 128; s > 0; s >>= 1){
    if(tid < s) red[tid] += red[tid + s];
    __syncthreads();
  }
  if(tid == 0) qk[plane] = red[0];
}

// ---------------- v pipeline per batch ----------
__global__ __launch_bounds__(256)
void k_v(const float* __restrict__ qk, const float* __restrict__ v1w,
         const float* __restrict__ v1b, const float* __restrict__ lnw,
         const float* __restrict__ lnb, const float* __restrict__ v2w,
         const float* __restrict__ v2b, float* __restrict__ vout){
  int b = blockIdx.x, tid = threadIdx.x;
  __shared__ float qs[256];
  __shared__ float part[256];
  __shared__ float v1s[16];
  __shared__ float vr[16];
  __shared__ float stats[2];
  qs[tid] = qk[b * 256 + tid];
  __syncthreads();
  int oc = tid >> 4, ln = tid & 15;
  float p = 0.f;
  #pragma unroll
  for(int j = 0; j < 16; j++){
    int cc = ln + j * 16;
    p = fmaf(v1w[oc * 256 + cc], qs[cc], p);
  }
  part[tid] = p;
  __syncthreads();
  if(tid < 16){
    float s = v1b[tid];
    for(int j = 0; j < 16; j++) s += part[tid * 16 + j];
    v1s[tid] = s;
  }
  __syncthreads();
  if(tid == 0){
    float mu = 0.f;
    for(int i = 0; i < 16; i++) mu += v1s[i];
    mu *= (1.f / 16.f);
    float var = 0.f;
    for(int i = 0; i < 16; i++){ float d = v1s[i] - mu; var += d * d; }
    var *= (1.f / 16.f);
    stats[0] = mu; stats[1] = rsqrtf(var + 1e-5f);
  }
  __syncthreads();
  if(tid < 16){
    float vv = (v1s[tid] - stats[0]) * stats[1] * lnw[tid] + lnb[tid];
    vr[tid] = fmaxf(vv, 0.f);
  }
  __syncthreads();
  float o = v2b[tid];
  #pragma unroll
  for(int j = 0; j < 16; j++) o = fmaf(v2w[tid * 16 + j], vr[j], o);
  vout[b * 256 + tid] = o;
}

// ---------------- out += vout (broadcast per plane) ----------
__global__ __launch_bounds__(256)
void k_final(float* __restrict__ out, const float* __restrict__ vout){
  int idx = blockIdx.x * 256 + threadIdx.x;
  int plane = idx >> 10;
  float4 p = *((float4*)out + idx);
  float vv = vout[plane];
  p.x += vv; p.y += vv; p.z += vv; p.w += vv;
  *((float4*)out + idx) = p;
}

extern "C" void kernel_launch(void* const* d_in, const int* in_sizes, int n_in,
                              void* d_out, int out_size, void* d_ws, size_t ws_size,
                              hipStream_t stream){
  const float* x      = (const float*)d_in[0];
  const float* conv_w = (const float*)d_in[1];
  const float* conv_b = (const float*)d_in[2];
  const float* fw3    = (const float*)d_in[3];
  const float* fw5    = (const float*)d_in[4];
  const float* fw7    = (const float*)d_in[5];
  const float* key_w  = (const float*)d_in[6];
  const float* key_b  = (const float*)d_in[7];
  const float* v1_w   = (const float*)d_in[8];
  const float* v1_b   = (const float*)d_in[9];
  const float* ln_w   = (const float*)d_in[10];
  const float* ln_b   = (const float*)d_in[11];
  const float* v2_w   = (const float*)d_in[12];
  const float* v2_b   = (const float*)d_in[13];
  float* out = (float*)d_out;

  const size_t PL = (size_t)B * C * N;     // 16,777,216 elements
  char* p = (char*)d_ws;
  ushort_t* ctxb = (ushort_t*)p;  p += PL * sizeof(ushort_t);          // 32 MB
  float* gates   = (float*)p;     p += (size_t)B * 4 * N * sizeof(float);
  float* kbuf    = (float*)p;     p += (size_t)B * N * sizeof(float);
  float* qkb     = (float*)p;     p += (size_t)B * C * sizeof(float);
  float* vout    = (float*)p;

  // 1. conv1x1 via bf16 MFMA -> ctxb (bf16, 256 ch) + gates (f32, 4 ch)
  k_conv1_mfma<<<dim3(1024, 5), 256, 0, stream>>>(x, conv_w, conv_b, ctxb, gates);
  // 2. fused dw3/dw5/dw7 chain -> out = full ctx_all (f32)
  k_dwchain<<<B * C, 512, 0, stream>>>(ctxb, fw3, fw5, fw7, gates, out);
  // 3. logits
  k_logits<<<1024, 256, 0, stream>>>(out, key_w, key_b, kbuf);
  // 4. softmax
  k_softmax<<<B, 256, 0, stream>>>(kbuf);
  // 5. qk
  k_qk<<<B * C, 256, 0, stream>>>(out, kbuf, qkb);
  // 6. v pipeline
  k_v<<<B, 256, 0, stream>>>(qkb, v1_w, v1_b, ln_w, ln_b, v2_w, v2_b, vout);
  // 7. final: out += v broadcast
  k_final<<<16384, 256, 0, stream>>>(out, vout);
}